// Round 4
// baseline (126.961 us; speedup 1.0000x reference)
//
#include <hip/hip_runtime.h>
#include <stdint.h>

// Problem constants (fixed by setup_inputs: B=4, N_obj=8, N_v=2048)
#define NPTS 2048
#define KNN  16
#define AK   64
#define TPB  256
#define FPT  8     // fps: points per thread
#define FPP  4     // fps: v2f pairs per thread
#define KPL  32    // knn: points per lane (one wave per anchor)
#define KPP  16    // knn: v2f pairs per lane

typedef unsigned long long u64;
typedef unsigned int u32;
typedef __attribute__((ext_vector_type(2))) float v2f;
#define UMAX 0xFFFFFFFFFFFFFFFFull

// Exact float32 helper (no FMA contraction -> match numpy reference bitwise)
__device__ __forceinline__ float sq3(float x, float y, float z) {
    return __fadd_rn(__fadd_rn(__fmul_rn(x, x), __fmul_rn(y, y)), __fmul_rn(z, z));
}

// ---------------------------------------------------------------------------
// DPP-only 64-lane reductions (zero DS ops). Sequence: quad_perm xor1/xor2,
// row_half_mirror (lane^7 within 16-row once quads uniform), row_mirror
// (lane^15), then row_bcast15 (rows 1,3 receive; mask 0xA) and row_bcast31
// (rows 2,3 receive; mask 0xC). Result lands in lane 63; v_readlane -> SGPR
// broadcasts it to the whole wave for free. Lanes without a valid DPP source
// keep `old` (bound_ctrl=false) -> combine is a harmless self-op.
// ---------------------------------------------------------------------------
template <int CTRL, int RMASK>
__device__ __forceinline__ u32 dpp32(u32 v) {
    return (u32)__builtin_amdgcn_update_dpp((int)v, (int)v, CTRL, RMASK, 0xF, false);
}

// max-combine step carrying (key, x, y, z) payload
template <int CTRL, int RMASK>
__device__ __forceinline__ void maxstep(u32& lo, u32& hi,
                                        float& x, float& y, float& z) {
    const u32 olo = dpp32<CTRL, RMASK>(lo);
    const u32 ohi = dpp32<CTRL, RMASK>(hi);
    const u32 ox = dpp32<CTRL, RMASK>(__float_as_uint(x));
    const u32 oy = dpp32<CTRL, RMASK>(__float_as_uint(y));
    const u32 oz = dpp32<CTRL, RMASK>(__float_as_uint(z));
    const u64 a = ((u64)hi << 32) | lo;
    const u64 b = ((u64)ohi << 32) | olo;
    if (b > a) {
        lo = olo; hi = ohi;
        x = __uint_as_float(ox); y = __uint_as_float(oy); z = __uint_as_float(oz);
    }
}

// min-combine step, key only
template <int CTRL, int RMASK>
__device__ __forceinline__ u64 minstep(u64 k) {
    const u32 olo = dpp32<CTRL, RMASK>((u32)k);
    const u32 ohi = dpp32<CTRL, RMASK>((u32)(k >> 32));
    const u64 o = ((u64)ohi << 32) | olo;
    return (o < k) ? o : k;
}

__device__ __forceinline__ u64 wave_min64(u64 k) {
    k = minstep<0xB1, 0xF>(k);   // quad_perm(1,0,3,2) = xor1
    k = minstep<0x4E, 0xF>(k);   // quad_perm(2,3,0,1) = xor2
    k = minstep<0x141, 0xF>(k);  // row_half_mirror
    k = minstep<0x140, 0xF>(k);  // row_mirror
    k = minstep<0x142, 0xA>(k);  // row_bcast15 -> rows 1,3
    k = minstep<0x143, 0xC>(k);  // row_bcast31 -> rows 2,3
    const u32 lo = (u32)__builtin_amdgcn_readlane((int)(u32)k, 63);
    const u32 hi = (u32)__builtin_amdgcn_readlane((int)(u32)(k >> 32), 63);
    return ((u64)hi << 32) | lo;
}

// ---------------------------------------------------------------------------
// Kernel 1: farthest-point sampling, one block (4 waves) per object.
// Points live entirely in registers (v2f pairs, packed-fp32 math). Per step:
// fused min-update + argmax scan tracking (val, j, coords); DPP-only wave
// reduction carrying coords; readlane; lane0 writes one 8-slot double-
// buffered LDS exchange; ONE barrier; redundant 4-way merge in registers.
// No point array in LDS, no bpermute, no dependent coord fetch.
// ---------------------------------------------------------------------------
__global__ __launch_bounds__(TPB) void fps_kernel(const float* __restrict__ pos,
                                                  int* __restrict__ anchors) {
#pragma clang fp contract(off)
    const int obj = blockIdx.x;
    const int t = threadIdx.x;
    const int wid = t >> 6, lane = t & 63;
    const float* pts = pos + (size_t)obj * NPTS * 3;

    __shared__ u64 skey[8];      // double-buffered per-wave winner keys
    __shared__ float4 scrd[8];   // double-buffered per-wave winner coords

    v2f px[FPP], py[FPP], pz[FPP], mind[FPP];
    float bv, bx, by, bz;
    u32 bj;
    {
        const float ax0 = pts[0], ay0 = pts[1], az0 = pts[2];
        bv = -1.0f; bj = 0; bx = by = bz = 0.0f;
        #pragma unroll
        for (int i = 0; i < FPP; i++) {
            const int jA = t + (2 * i) * TPB;      // jA < jB: ascending scan
            const int jB = t + (2 * i + 1) * TPB;  // order for argmax ties
            v2f X, Y, Z;
            X.x = pts[jA * 3 + 0]; Y.x = pts[jA * 3 + 1]; Z.x = pts[jA * 3 + 2];
            X.y = pts[jB * 3 + 0]; Y.y = pts[jB * 3 + 1]; Z.y = pts[jB * 3 + 2];
            px[i] = X; py[i] = Y; pz[i] = Z;
            const v2f dx = X - ax0, dy = Y - ay0, dz = Z - az0;
            const v2f d2 = dx * dx + dy * dy + dz * dz;  // ((x2+y2)+z2), no fma
            mind[i] = d2;
            if (d2.x > bv) { bv = d2.x; bj = (u32)jA; bx = X.x; by = Y.x; bz = Z.x; }
            if (d2.y > bv) { bv = d2.y; bj = (u32)jB; bx = X.y; by = Y.y; bz = Z.y; }
        }
    }
    if (t == 0) anchors[obj * AK + 0] = 0;

    for (int s = 1; s < AK; s++) {
        // mind >= 0 -> float bits order-monotonic; ~j -> smaller j wins ties
        // under max (matches jnp.argmax first-occurrence).
        u32 klo = ~bj, khi = __float_as_uint(bv);
        float wx = bx, wy = by, wz = bz;
        maxstep<0xB1, 0xF>(klo, khi, wx, wy, wz);
        maxstep<0x4E, 0xF>(klo, khi, wx, wy, wz);
        maxstep<0x141, 0xF>(klo, khi, wx, wy, wz);
        maxstep<0x140, 0xF>(klo, khi, wx, wy, wz);
        maxstep<0x142, 0xA>(klo, khi, wx, wy, wz);
        maxstep<0x143, 0xC>(klo, khi, wx, wy, wz);
        // lane 63 holds the wave winner -> SGPRs (uniform)
        const u32 wlo = (u32)__builtin_amdgcn_readlane((int)klo, 63);
        const u32 whi = (u32)__builtin_amdgcn_readlane((int)khi, 63);
        const u32 ux = (u32)__builtin_amdgcn_readlane((int)__float_as_uint(wx), 63);
        const u32 uy = (u32)__builtin_amdgcn_readlane((int)__float_as_uint(wy), 63);
        const u32 uz = (u32)__builtin_amdgcn_readlane((int)__float_as_uint(wz), 63);

        const int side = (s & 1) * 4;
        if (lane == 0) {
            skey[side + wid] = ((u64)whi << 32) | wlo;
            scrd[side + wid] = make_float4(__uint_as_float(ux), __uint_as_float(uy),
                                           __uint_as_float(uz), 0.0f);
        }
        __syncthreads();   // only barrier per step (slots double-buffered)

        u64 ka = skey[side + 0];
        float4 ca = scrd[side + 0];
        { const u64 kb = skey[side + 1]; const float4 cb = scrd[side + 1];
          if (kb > ka) { ka = kb; ca = cb; } }
        { const u64 kb = skey[side + 2]; const float4 cb = scrd[side + 2];
          if (kb > ka) { ka = kb; ca = cb; } }
        { const u64 kb = skey[side + 3]; const float4 cb = scrd[side + 3];
          if (kb > ka) { ka = kb; ca = cb; } }
        if (t == 0) anchors[obj * AK + s] = (int)(~(u32)ka);
        if (s == AK - 1) break;   // no update needed after last anchor

        // fused min-update + argmax scan (exact: direct (p-b)^2 like lax.scan)
        bv = -1.0f; bj = 0;
        #pragma unroll
        for (int i = 0; i < FPP; i++) {
            const v2f dx = px[i] - ca.x, dy = py[i] - ca.y, dz = pz[i] - ca.z;
            const v2f d2 = dx * dx + dy * dy + dz * dz;
            v2f nm;
            nm.x = fminf(mind[i].x, d2.x);
            nm.y = fminf(mind[i].y, d2.y);
            mind[i] = nm;
            if (nm.x > bv) { bv = nm.x; bj = (u32)(t + (2 * i) * TPB);
                             bx = px[i].x; by = py[i].x; bz = pz[i].x; }
            if (nm.y > bv) { bv = nm.y; bj = (u32)(t + (2 * i + 1) * TPB);
                             bx = px[i].y; by = py[i].y; bz = pz[i].y; }
        }
    }
}

// ---------------------------------------------------------------------------
// Kernel 2: KNN dist-vec + gather + concat. ONE WAVE per anchor, 4 anchors
// per block. Keys (sortbits<<32)|j unique -> single u64 compares. Per-lane
// sorted top-2 cache; rare refill (lane contributed >2 of global top-16,
// P~0.14/wave) rescans with threshold > thr — exact because pops leave in
// ascending key order. Wave-min is DPP+readlane (no DS ops).
// ---------------------------------------------------------------------------
__global__ __launch_bounds__(TPB) void knn_gather_kernel(
    const float* __restrict__ pos, const float* __restrict__ vel,
    const float* __restrict__ phys, const float* __restrict__ refp,
    const int* __restrict__ anchors, float* __restrict__ out) {
#pragma clang fp contract(off)
    const int t = threadIdx.x;
    const int wid = t >> 6, lane = t & 63;
    const int g = blockIdx.x * 4 + wid;   // global anchor id (obj*64 + k)
    const int obj = g >> 6;

    __shared__ float sX[NPTS], sY[NPTS], sZ[NPTS];   // SoA, bank-perfect
    const float* pts = pos + (size_t)obj * NPTS * 3;
    #pragma unroll
    for (int i = 0; i < FPT; i++) {
        const int j = t + i * TPB;
        sX[j] = pts[j * 3 + 0];
        sY[j] = pts[j * 3 + 1];
        sZ[j] = pts[j * 3 + 2];
    }
    const int a = anchors[g];   // global read, no LDS hazard
    __syncthreads();            // the only barrier

    const float ax = sX[a], ay = sY[a], az = sZ[a];
    const float sqa = sq3(ax, ay, az);

    // d2 row exactly as reference: (sq_a + sq_j) - 2*dot; packed-fp32 pairs,
    // per-component rounding identical to the scalar __f*_rn sequence.
    u64 k[KPL];
    #pragma unroll
    for (int i = 0; i < KPP; i++) {
        const int jA = lane + (2 * i) * 64, jB = lane + (2 * i + 1) * 64;
        v2f X, Y, Z;
        X.x = sX[jA]; Y.x = sY[jA]; Z.x = sZ[jA];
        X.y = sX[jB]; Y.y = sY[jB]; Z.y = sZ[jB];
        const v2f sqj = X * X + Y * Y + Z * Z;          // ((x2+y2)+z2)
        const v2f dot = ax * X + ay * Y + az * Z;       // ((ax*x+ay*y)+az*z)
        const v2f d2 = (sqa + sqj) - 2.0f * dot;
        u32 b0 = __float_as_uint(d2.x);
        b0 ^= (b0 & 0x80000000u) ? 0xFFFFFFFFu : 0x80000000u;  // sortable
        u32 b1 = __float_as_uint(d2.y);
        b1 ^= (b1 & 0x80000000u) ? 0xFFFFFFFFu : 0x80000000u;
        k[2 * i]     = (jA == a) ? UMAX : (((u64)b0 << 32) | (u32)jA);
        k[2 * i + 1] = (jB == a) ? UMAX : (((u64)b1 << 32) | (u32)jB);
    }

    // per-lane 2 smallest, ascending: c0 < c1 (keys unique)
    u64 c0 = UMAX, c1 = UMAX;
    #pragma unroll
    for (int i = 0; i < KPL; i++) c0 = (k[i] < c0) ? k[i] : c0;
    #pragma unroll
    for (int i = 0; i < KPL; i++) {
        const u64 v = (k[i] > c0) ? k[i] : UMAX; c1 = (v < c1) ? v : c1;
    }

    float accx = 0.f, accy = 0.f, accz = 0.f;
    u64 thr = 0;
    for (int r = 0; r < KNN; r++) {
        if (c0 == UMAX) {   // rare refill: 2 smallest keys > thr
            #pragma unroll
            for (int i = 0; i < KPL; i++) {
                const u64 v = (k[i] > thr) ? k[i] : UMAX; c0 = (v < c0) ? v : c0;
            }
            #pragma unroll
            for (int i = 0; i < KPL; i++) {
                const u64 v = (k[i] > c0) ? k[i] : UMAX; c1 = (v < c1) ? v : c1;
            }
        }
        const u64 w = wave_min64(c0);       // global min; keys unique
        const int winj = (int)(u32)w;
        // accumulate in ascending-distance order (== top_k output order);
        // uniform LDS reads broadcast, off the pop critical path.
        accx = __fadd_rn(accx, __fsub_rn(sX[winj], ax));
        accy = __fadd_rn(accy, __fsub_rn(sY[winj], ay));
        accz = __fadd_rn(accz, __fsub_rn(sZ[winj], az));
        if (c0 == w) {                       // exactly one lane pops
            thr = c0; c0 = c1; c1 = UMAX;
        }
    }

    if (lane == 0) {
        float* o = out + (size_t)g * 12;
        o[0] = __fmul_rn(accx, 0.0625f);   // /16 exact as *2^-4
        o[1] = __fmul_rn(accy, 0.0625f);
        o[2] = __fmul_rn(accz, 0.0625f);
        const size_t base = (size_t)obj * NPTS * 3 + (size_t)a * 3;
        o[3] = vel[base + 0];
        o[4] = vel[base + 1];
        o[5] = vel[base + 2];
        o[6] = __fsub_rn(pos[base + 0], refp[base + 0]);
        o[7] = __fsub_rn(pos[base + 1], refp[base + 1]);
        o[8] = __fsub_rn(pos[base + 2], refp[base + 2]);
        const float* ph = phys + (size_t)obj * 3;
        o[9]  = ph[0];
        o[10] = ph[1];
        o[11] = ph[2];
    }
}

extern "C" void kernel_launch(void* const* d_in, const int* in_sizes, int n_in,
                              void* d_out, int out_size, void* d_ws, size_t ws_size,
                              hipStream_t stream) {
    const float* pos  = (const float*)d_in[0];  // (4,8,2048,3)
    const float* vel  = (const float*)d_in[1];  // (4,8,2048,3)
    const float* phys = (const float*)d_in[2];  // (4,8,3)
    const float* refp = (const float*)d_in[3];  // (4,8,2048,3)
    float* out = (float*)d_out;                 // (4,8,64,12)

    const int n_obj = in_sizes[2] / 3;          // 32 objects
    int* anchors = (int*)d_ws;                  // n_obj * 64 ints

    fps_kernel<<<n_obj, TPB, 0, stream>>>(pos, anchors);
    knn_gather_kernel<<<n_obj * AK / 4, TPB, 0, stream>>>(pos, vel, phys, refp,
                                                          anchors, out);
}

// Round 5
// 117.390 us; speedup vs baseline: 1.0815x; 1.0815x over previous
//
#include <hip/hip_runtime.h>
#include <stdint.h>

// Problem constants (fixed by setup_inputs: B=4, N_obj=8, N_v=2048)
#define NPTS 2048
#define KNN  16
#define AK   64
#define TPB  256
#define FPT  8     // fps: points per thread
#define FPP  4     // fps: v2f pairs per thread
#define KPL  32    // knn: points per lane (one wave per anchor)
#define KPP  16    // knn: v2f pairs per lane

typedef unsigned long long u64;
typedef unsigned int u32;
typedef __attribute__((ext_vector_type(2))) float v2f;
#define UMAX 0xFFFFFFFFFFFFFFFFull

// Exact float32 helper (no FMA contraction -> match numpy reference bitwise)
__device__ __forceinline__ float sq3(float x, float y, float z) {
    return __fadd_rn(__fadd_rn(__fmul_rn(x, x), __fmul_rn(y, y)), __fmul_rn(z, z));
}

// ---------------------------------------------------------------------------
// DPP primitives. Canonical GCN 64-lane reduction sequence:
// quad_perm xor1 / quad_perm xor2 / row_half_mirror / row_mirror /
// row_bcast15 (row_mask 0xA) / row_bcast31 (row_mask 0xC); result in lane 63,
// v_readlane 63 -> SGPR broadcasts it. bound_ctrl=false + old=src => masked
// lanes self-combine harmlessly.
// ---------------------------------------------------------------------------
template <int CTRL, int RMASK>
__device__ __forceinline__ u32 dpp32(u32 v) {
    return (u32)__builtin_amdgcn_update_dpp((int)v, (int)v, CTRL, RMASK, 0xF, false);
}

#define FMAX_STEP(CTRL, RMASK) \
    m = fmaxf(m, __uint_as_float(dpp32<CTRL, RMASK>(__float_as_uint(m))))
#define UMIN_STEP(CTRL, RMASK) \
    { const u32 o_ = dpp32<CTRL, RMASK>(c); c = (o_ < c) ? o_ : c; }

// full-wave max of a non-negative float, result uniform (via lane 63)
__device__ __forceinline__ float wave_fmax(float m) {
    FMAX_STEP(0xB1, 0xF);   // quad_perm(1,0,3,2) = xor1
    FMAX_STEP(0x4E, 0xF);   // quad_perm(2,3,0,1) = xor2
    FMAX_STEP(0x141, 0xF);  // row_half_mirror
    FMAX_STEP(0x140, 0xF);  // row_mirror
    FMAX_STEP(0x142, 0xA);  // row_bcast15 -> rows 1,3
    FMAX_STEP(0x143, 0xC);  // row_bcast31 -> rows 2,3
    return __uint_as_float((u32)__builtin_amdgcn_readlane(
        (int)__float_as_uint(m), 63));
}

// full-wave min of a u32, result uniform (via lane 63)
__device__ __forceinline__ u32 wave_umin(u32 c) {
    UMIN_STEP(0xB1, 0xF);
    UMIN_STEP(0x4E, 0xF);
    UMIN_STEP(0x141, 0xF);
    UMIN_STEP(0x140, 0xF);
    UMIN_STEP(0x142, 0xA);
    UMIN_STEP(0x143, 0xC);
    return (u32)__builtin_amdgcn_readlane((int)c, 63);
}

// u64 min-combine step (knn key reduction) — kept identical to validated R4
template <int CTRL, int RMASK>
__device__ __forceinline__ u64 minstep(u64 k) {
    const u32 olo = dpp32<CTRL, RMASK>((u32)k);
    const u32 ohi = dpp32<CTRL, RMASK>((u32)(k >> 32));
    const u64 o = ((u64)ohi << 32) | olo;
    return (o < k) ? o : k;
}

__device__ __forceinline__ u64 wave_min64(u64 k) {
    k = minstep<0xB1, 0xF>(k);
    k = minstep<0x4E, 0xF>(k);
    k = minstep<0x141, 0xF>(k);
    k = minstep<0x140, 0xF>(k);
    k = minstep<0x142, 0xA>(k);
    k = minstep<0x143, 0xC>(k);
    const u32 lo = (u32)__builtin_amdgcn_readlane((int)(u32)k, 63);
    const u32 hi = (u32)__builtin_amdgcn_readlane((int)(u32)(k >> 32), 63);
    return ((u64)hi << 32) | lo;
}

// ---------------------------------------------------------------------------
// Kernel 1: farthest-point sampling, one block (4 waves) per object.
// Points live in registers. Per step:
//   scan: fused min-update + argmax tracking (val, j, coords) in regs
//   reduce: DPP f32-max on value -> readlane; then u32-min over candidate j
//           (exactly the u64-key winner: max value, smallest j on ties)
//   exchange: THE WINNER LANE writes key+coords to its wave's slot (it holds
//           the coords in registers — no dependent LDS coord fetch at all),
//           ONE barrier, redundant 4-way payload merge in registers.
// ---------------------------------------------------------------------------
__global__ __launch_bounds__(TPB) void fps_kernel(const float* __restrict__ pos,
                                                  int* __restrict__ anchors) {
#pragma clang fp contract(off)
    const int obj = blockIdx.x;
    const int t = threadIdx.x;
    const int wid = t >> 6;
    const float* pts = pos + (size_t)obj * NPTS * 3;

    __shared__ u64 skey[8];      // double-buffered per-wave winner keys
    __shared__ float4 scrd[8];   // double-buffered per-wave winner coords

    v2f px[FPP], py[FPP], pz[FPP], mind[FPP];
    float bv, bx, by, bz;
    u32 bj;
    {
        const float ax0 = pts[0], ay0 = pts[1], az0 = pts[2];
        bv = -1.0f; bj = 0; bx = by = bz = 0.0f;
        #pragma unroll
        for (int i = 0; i < FPP; i++) {
            const int jA = t + (2 * i) * TPB;      // jA < jB: ascending j per
            const int jB = t + (2 * i + 1) * TPB;  // lane for argmax ties
            v2f X, Y, Z;
            X.x = pts[jA * 3 + 0]; Y.x = pts[jA * 3 + 1]; Z.x = pts[jA * 3 + 2];
            X.y = pts[jB * 3 + 0]; Y.y = pts[jB * 3 + 1]; Z.y = pts[jB * 3 + 2];
            px[i] = X; py[i] = Y; pz[i] = Z;
            const v2f dx = X - ax0, dy = Y - ay0, dz = Z - az0;
            const v2f d2 = dx * dx + dy * dy + dz * dz;  // ((x2+y2)+z2), no fma
            mind[i] = d2;
            if (d2.x > bv) { bv = d2.x; bj = (u32)jA; bx = X.x; by = Y.x; bz = Z.x; }
            if (d2.y > bv) { bv = d2.y; bj = (u32)jB; bx = X.y; by = Y.y; bz = Z.y; }
        }
    }
    if (t == 0) anchors[obj * AK + 0] = 0;

    for (int s = 1; s < AK; s++) {
        // Phase 1: wave max of the value alone (cheap DPP f32 chain).
        const float wmax = wave_fmax(bv);
        // Phase 2: smallest j among lanes achieving wmax. Per-lane bj is the
        // smallest local j at bv (strict > in scan), so global first
        // occurrence = min over candidates — matches jnp.argmax exactly.
        const u32 cand = (bv == wmax) ? bj : 0xFFFFFFFFu;
        const u32 wj = wave_umin(cand);

        const int side = (s & 1) * 4;
        if (bv == wmax && bj == wj) {   // exactly one lane per wave (j owner)
            // key = (bits(value)<<32) | ~j : max key == max val, then min j
            skey[side + wid] = ((u64)__float_as_uint(wmax) << 32) | (u32)(~wj);
            scrd[side + wid] = make_float4(bx, by, bz, 0.0f);
        }
        __syncthreads();   // only barrier per step (slots double-buffered)

        u64 ka = skey[side + 0];
        float4 ca = scrd[side + 0];
        { const u64 kb = skey[side + 1]; const float4 cb = scrd[side + 1];
          if (kb > ka) { ka = kb; ca = cb; } }
        { const u64 kb = skey[side + 2]; const float4 cb = scrd[side + 2];
          if (kb > ka) { ka = kb; ca = cb; } }
        { const u64 kb = skey[side + 3]; const float4 cb = scrd[side + 3];
          if (kb > ka) { ka = kb; ca = cb; } }
        if (t == 0) anchors[obj * AK + s] = (int)(~(u32)ka);
        if (s == AK - 1) break;   // no update needed after last anchor

        // fused min-update + argmax scan (exact: direct (p-b)^2 like lax.scan)
        bv = -1.0f; bj = 0;
        #pragma unroll
        for (int i = 0; i < FPP; i++) {
            const v2f dx = px[i] - ca.x, dy = py[i] - ca.y, dz = pz[i] - ca.z;
            const v2f d2 = dx * dx + dy * dy + dz * dz;
            v2f nm;
            nm.x = fminf(mind[i].x, d2.x);
            nm.y = fminf(mind[i].y, d2.y);
            mind[i] = nm;
            if (nm.x > bv) { bv = nm.x; bj = (u32)(t + (2 * i) * TPB);
                             bx = px[i].x; by = py[i].x; bz = pz[i].x; }
            if (nm.y > bv) { bv = nm.y; bj = (u32)(t + (2 * i + 1) * TPB);
                             bx = px[i].y; by = py[i].y; bz = pz[i].y; }
        }
    }
}

// ---------------------------------------------------------------------------
// Kernel 2: KNN dist-vec + gather + concat. ONE WAVE per anchor, 4 anchors
// per block. UNCHANGED from the validated R4 kernel (minimal-diff): per-lane
// sorted top-2 cache, rare threshold refill, DPP u64 wave-min.
// ---------------------------------------------------------------------------
__global__ __launch_bounds__(TPB) void knn_gather_kernel(
    const float* __restrict__ pos, const float* __restrict__ vel,
    const float* __restrict__ phys, const float* __restrict__ refp,
    const int* __restrict__ anchors, float* __restrict__ out) {
#pragma clang fp contract(off)
    const int t = threadIdx.x;
    const int wid = t >> 6, lane = t & 63;
    const int g = blockIdx.x * 4 + wid;   // global anchor id (obj*64 + k)
    const int obj = g >> 6;

    __shared__ float sX[NPTS], sY[NPTS], sZ[NPTS];   // SoA, bank-perfect
    const float* pts = pos + (size_t)obj * NPTS * 3;
    #pragma unroll
    for (int i = 0; i < FPT; i++) {
        const int j = t + i * TPB;
        sX[j] = pts[j * 3 + 0];
        sY[j] = pts[j * 3 + 1];
        sZ[j] = pts[j * 3 + 2];
    }
    const int a = anchors[g];   // global read, no LDS hazard
    __syncthreads();            // the only barrier

    const float ax = sX[a], ay = sY[a], az = sZ[a];
    const float sqa = sq3(ax, ay, az);

    // d2 row exactly as reference: (sq_a + sq_j) - 2*dot; packed-fp32 pairs,
    // per-component rounding identical to the scalar __f*_rn sequence.
    u64 k[KPL];
    #pragma unroll
    for (int i = 0; i < KPP; i++) {
        const int jA = lane + (2 * i) * 64, jB = lane + (2 * i + 1) * 64;
        v2f X, Y, Z;
        X.x = sX[jA]; Y.x = sY[jA]; Z.x = sZ[jA];
        X.y = sX[jB]; Y.y = sY[jB]; Z.y = sZ[jB];
        const v2f sqj = X * X + Y * Y + Z * Z;          // ((x2+y2)+z2)
        const v2f dot = ax * X + ay * Y + az * Z;       // ((ax*x+ay*y)+az*z)
        const v2f d2 = (sqa + sqj) - 2.0f * dot;
        u32 b0 = __float_as_uint(d2.x);
        b0 ^= (b0 & 0x80000000u) ? 0xFFFFFFFFu : 0x80000000u;  // sortable
        u32 b1 = __float_as_uint(d2.y);
        b1 ^= (b1 & 0x80000000u) ? 0xFFFFFFFFu : 0x80000000u;
        k[2 * i]     = (jA == a) ? UMAX : (((u64)b0 << 32) | (u32)jA);
        k[2 * i + 1] = (jB == a) ? UMAX : (((u64)b1 << 32) | (u32)jB);
    }

    // per-lane 2 smallest, ascending: c0 < c1 (keys unique)
    u64 c0 = UMAX, c1 = UMAX;
    #pragma unroll
    for (int i = 0; i < KPL; i++) c0 = (k[i] < c0) ? k[i] : c0;
    #pragma unroll
    for (int i = 0; i < KPL; i++) {
        const u64 v = (k[i] > c0) ? k[i] : UMAX; c1 = (v < c1) ? v : c1;
    }

    float accx = 0.f, accy = 0.f, accz = 0.f;
    u64 thr = 0;
    for (int r = 0; r < KNN; r++) {
        if (c0 == UMAX) {   // rare refill: 2 smallest keys > thr
            #pragma unroll
            for (int i = 0; i < KPL; i++) {
                const u64 v = (k[i] > thr) ? k[i] : UMAX; c0 = (v < c0) ? v : c0;
            }
            #pragma unroll
            for (int i = 0; i < KPL; i++) {
                const u64 v = (k[i] > c0) ? k[i] : UMAX; c1 = (v < c1) ? v : c1;
            }
        }
        const u64 w = wave_min64(c0);       // global min; keys unique
        const int winj = (int)(u32)w;
        // accumulate in ascending-distance order (== top_k output order);
        // uniform LDS reads broadcast, off the pop critical path.
        accx = __fadd_rn(accx, __fsub_rn(sX[winj], ax));
        accy = __fadd_rn(accy, __fsub_rn(sY[winj], ay));
        accz = __fadd_rn(accz, __fsub_rn(sZ[winj], az));
        if (c0 == w) {                       // exactly one lane pops
            thr = c0; c0 = c1; c1 = UMAX;
        }
    }

    if (lane == 0) {
        float* o = out + (size_t)g * 12;
        o[0] = __fmul_rn(accx, 0.0625f);   // /16 exact as *2^-4
        o[1] = __fmul_rn(accy, 0.0625f);
        o[2] = __fmul_rn(accz, 0.0625f);
        const size_t base = (size_t)obj * NPTS * 3 + (size_t)a * 3;
        o[3] = vel[base + 0];
        o[4] = vel[base + 1];
        o[5] = vel[base + 2];
        o[6] = __fsub_rn(pos[base + 0], refp[base + 0]);
        o[7] = __fsub_rn(pos[base + 1], refp[base + 1]);
        o[8] = __fsub_rn(pos[base + 2], refp[base + 2]);
        const float* ph = phys + (size_t)obj * 3;
        o[9]  = ph[0];
        o[10] = ph[1];
        o[11] = ph[2];
    }
}

extern "C" void kernel_launch(void* const* d_in, const int* in_sizes, int n_in,
                              void* d_out, int out_size, void* d_ws, size_t ws_size,
                              hipStream_t stream) {
    const float* pos  = (const float*)d_in[0];  // (4,8,2048,3)
    const float* vel  = (const float*)d_in[1];  // (4,8,2048,3)
    const float* phys = (const float*)d_in[2];  // (4,8,3)
    const float* refp = (const float*)d_in[3];  // (4,8,2048,3)
    float* out = (float*)d_out;                 // (4,8,64,12)

    const int n_obj = in_sizes[2] / 3;          // 32 objects
    int* anchors = (int*)d_ws;                  // n_obj * 64 ints

    fps_kernel<<<n_obj, TPB, 0, stream>>>(pos, anchors);
    knn_gather_kernel<<<n_obj * AK / 4, TPB, 0, stream>>>(pos, vel, phys, refp,
                                                          anchors, out);
}